// Round 12
// baseline (806.084 us; speedup 1.0000x reference)
//
#include <hip/hip_runtime.h>
#include <hip/hip_cooperative_groups.h>
#include <hip/hip_bf16.h>
#include <math.h>

namespace cg = cooperative_groups;

// N = 65536 nodes, E = 524288 edges, HID = 128, 128 graphs x 512 nodes
// fp32 throughout: absmax threshold ~9.8e-8 forbids bf16 MFMA.
// ONE cooperative dispatch: zero -> CSR build + weight fold -> 3x(gemm->agg)
// -> topk+MLP, phases separated by grid.sync(). Kernel bodies = round-9's
// proven versions (gemm BM=128/256thr single-buffer 44us; agg FLAT=16 45us).
// Rounds 6/7/10/11 all showed structural edits to gemm/agg regress; the
// remaining bucket was ~27us of dispatch boundaries + ramps -- removed here.

#define SLOTS 48
#define FLAT  16
#define ASTRIDE 257
#define WSTRIDE 140
// smem carve (floats): gemm As[32*257]=8224 | Ws[32*140]=4480  -> 12704 total
#define SMEM_FLOATS (32 * ASTRIDE + 32 * WSTRIDE)

static __device__ __forceinline__ float4 f4add(float4 a, float4 b) {
    return make_float4(a.x + b.x, a.y + b.y, a.z + b.z, a.w + b.w);
}
static __device__ __forceinline__ float4 f4fma(float s, float4 a, float4 acc) {
    return make_float4(fmaf(s, a.x, acc.x), fmaf(s, a.y, acc.y),
                       fmaf(s, a.z, acc.z), fmaf(s, a.w, acc.w));
}

// ---------------- weight fold row: [embW;embb](129x128) @ W0 ----------------
static __device__ void fold_row(int r, const float* __restrict__ embW,
                                const float* __restrict__ embb,
                                const float* __restrict__ W0,
                                float* __restrict__ W01, float* __restrict__ b01,
                                float* smem)
{
    float* rs   = smem;        // 128
    float* part = smem + 128;  // 256
    const int t = threadIdx.x;
    const int c = t & 127, q = t >> 7;
    if (t < 128) rs[t] = (r < 128) ? embW[r * 128 + t] : embb[t];
    __syncthreads();
    float s = 0.f;
    const int k0 = q * 64;
#pragma unroll 8
    for (int k = k0; k < k0 + 64; k++) s = fmaf(rs[k], W0[k * 128 + c], s);
    part[t] = s;
    __syncthreads();
    if (q == 0) {
        float v = part[c] + part[c + 128];
        if (r < 128) W01[r * 128 + c] = v;
        else         b01[c] = v;
    }
    __syncthreads();
}

// ---------------- gemm tile: 128 rows x 128 cols, K=128 ---------------------
// Round-5/8/9 proven body. Epilogue: out = (acc+bias)*rsqrt(cnt[row]+1).
static __device__ void gemm_tile(const float* __restrict__ A,
                                 const float* __restrict__ W,
                                 const float* __restrict__ bias,
                                 const int* __restrict__ cnt,
                                 float* __restrict__ out, int tile, float* smem)
{
    float* As = smem;                 // [k][m] transposed, stride 257
    float* Ws = smem + 32 * ASTRIDE;  // [k][c'] swizzled, stride 140
    const int tid  = threadIdx.x;
    const int rb   = tile * 128;
    const int tc   = tid & 15;
    const int tr   = tid >> 4;
    const int colg = tc * 8;
    const int cswz = colg + ((colg >> 5) << 2);
    const int rowg = tr * 8;

    const int a_kq = tid & 7;
    const int a_m  = tid >> 3;
    const int w_c  = (tid & 31) * 4;
    const int w_cs = w_c + ((w_c >> 5) << 2);
    const int w_k  = tid >> 5;

    float acc[8][8];
#pragma unroll
    for (int i = 0; i < 8; i++)
#pragma unroll
        for (int j = 0; j < 8; j++) acc[i][j] = 0.f;

    float4 areg[4], wreg[4];
#pragma unroll
    for (int t = 0; t < 4; t++)
        areg[t] = *(const float4*)&A[(size_t)(rb + t * 32 + a_m) * 128 + a_kq * 4];
#pragma unroll
    for (int t = 0; t < 4; t++)
        wreg[t] = *(const float4*)&W[(size_t)(t * 8 + w_k) * 128 + w_c];

#pragma unroll 1
    for (int k0 = 0; k0 < 128; k0 += 32) {
#pragma unroll
        for (int t = 0; t < 4; t++) {
            const int m = t * 32 + a_m;
            const float4 av = areg[t];
            As[(a_kq * 4 + 0) * ASTRIDE + m] = av.x;
            As[(a_kq * 4 + 1) * ASTRIDE + m] = av.y;
            As[(a_kq * 4 + 2) * ASTRIDE + m] = av.z;
            As[(a_kq * 4 + 3) * ASTRIDE + m] = av.w;
        }
#pragma unroll
        for (int t = 0; t < 4; t++)
            *(float4*)&Ws[(t * 8 + w_k) * WSTRIDE + w_cs] = wreg[t];
        __syncthreads();
        if (k0 < 96) {
#pragma unroll
            for (int t = 0; t < 4; t++)
                areg[t] = *(const float4*)&A[(size_t)(rb + t * 32 + a_m) * 128 + k0 + 32 + a_kq * 4];
#pragma unroll
            for (int t = 0; t < 4; t++)
                wreg[t] = *(const float4*)&W[(size_t)(k0 + 32 + t * 8 + w_k) * 128 + w_c];
        }
#pragma unroll 8
        for (int kk = 0; kk < 32; kk++) {
            float4 a0 = *(const float4*)&As[kk * ASTRIDE + rowg];
            float4 a1 = *(const float4*)&As[kk * ASTRIDE + rowg + 4];
            float4 b0 = *(const float4*)&Ws[kk * WSTRIDE + cswz];
            float4 b1 = *(const float4*)&Ws[kk * WSTRIDE + cswz + 4];
            float av[8] = {a0.x, a0.y, a0.z, a0.w, a1.x, a1.y, a1.z, a1.w};
            float bv[8] = {b0.x, b0.y, b0.z, b0.w, b1.x, b1.y, b1.z, b1.w};
#pragma unroll
            for (int i = 0; i < 8; i++)
#pragma unroll
                for (int j = 0; j < 8; j++) acc[i][j] = fmaf(av[i], bv[j], acc[i][j]);
        }
        __syncthreads();
    }

    float4 bb0 = make_float4(0.f, 0.f, 0.f, 0.f), bb1 = bb0;
    if (bias) {
        bb0 = *(const float4*)&bias[colg];
        bb1 = *(const float4*)&bias[colg + 4];
    }
#pragma unroll
    for (int i = 0; i < 8; i++) {
        const int row  = rb + rowg + i;
        const float sc = rsqrtf((float)(cnt[row] + 1));
        float4 o0, o1;
        o0.x = (acc[i][0] + bb0.x) * sc;  o0.y = (acc[i][1] + bb0.y) * sc;
        o0.z = (acc[i][2] + bb0.z) * sc;  o0.w = (acc[i][3] + bb0.w) * sc;
        o1.x = (acc[i][4] + bb1.x) * sc;  o1.y = (acc[i][5] + bb1.y) * sc;
        o1.z = (acc[i][6] + bb1.z) * sc;  o1.w = (acc[i][7] + bb1.w) * sc;
        *(float4*)&out[(size_t)row * 128 + colg]     = o0;
        *(float4*)&out[(size_t)row * 128 + colg + 4] = o1;
    }
}

// ---------------- aggregate group: 8 nodes per 256-thread block -------------
static __device__ void agg_group(const float* __restrict__ hs,
                                 const int* __restrict__ csr_pad,
                                 const int* __restrict__ cnt,
                                 const float* __restrict__ bias,
                                 float* __restrict__ hout,
                                 const float* __restrict__ pool_p,
                                 float* __restrict__ scores, int gg)
{
    const int grp  = threadIdx.x >> 5;
    const int lane = threadIdx.x & 31;
    const int node = gg * 8 + grp;
    const float4* __restrict__ hv = (const float4*)hs;

    const int deg = cnt[node];
    const int e0  = node * SLOTS;

    int   ix[FLAT];
    float mk[FLAT];
#pragma unroll
    for (int j = 0; j < FLAT; j++) {
        const int raw = csr_pad[e0 + j];   // always in-bounds memory
        const bool v  = j < deg;
        ix[j] = v ? raw : node;            // clamp poison before use
        mk[j] = v ? 1.f : 0.f;
    }

    float4 self = hv[(size_t)node * 32 + lane];
    float4 r[FLAT];
#pragma unroll
    for (int j = 0; j < FLAT; j++)
        r[j] = hv[(size_t)ix[j] * 32 + lane];
    asm volatile("" ::: "memory");  // keep the gathers in flight before use

    float4 a0 = self;
    float4 a1 = make_float4(0.f, 0.f, 0.f, 0.f);
    float4 a2 = a1, a3 = a1;
#pragma unroll
    for (int j = 0; j < FLAT; j += 4) {
        a0 = f4fma(mk[j + 0], r[j + 0], a0);
        a1 = f4fma(mk[j + 1], r[j + 1], a1);
        a2 = f4fma(mk[j + 2], r[j + 2], a2);
        a3 = f4fma(mk[j + 3], r[j + 3], a3);
    }
    const int dcap = deg < SLOTS ? deg : SLOTS;
    for (int j = FLAT; j < dcap; j++) {  // rare tail (deg > 16)
        a1 = f4add(a1, hv[(size_t)csr_pad[e0 + j] * 32 + lane]);
    }

    float4 s = f4add(f4add(a0, a1), f4add(a2, a3));
    const float dv = rsqrtf((float)(deg + 1));
    const float4 bb = ((const float4*)bias)[lane];
    float4 o;
    o.x = fmaxf(fmaf(s.x, dv, bb.x), 0.f);
    o.y = fmaxf(fmaf(s.y, dv, bb.y), 0.f);
    o.z = fmaxf(fmaf(s.z, dv, bb.z), 0.f);
    o.w = fmaxf(fmaf(s.w, dv, bb.w), 0.f);
    ((float4*)hout)[(size_t)node * 32 + lane] = o;

    if (scores) {  // wave-uniform (fused pooling score, last layer only)
        float4 pv = ((const float4*)pool_p)[lane];
        float d  = o.x * pv.x + o.y * pv.y + o.z * pv.z + o.w * pv.w;
        float nn = pv.x * pv.x + pv.y * pv.y + pv.z * pv.z + pv.w * pv.w;
#pragma unroll
        for (int off = 16; off > 0; off >>= 1) {
            d  += __shfl_xor(d, off);
            nn += __shfl_xor(nn, off);
        }
        if (lane == 0) scores[node] = d * rsqrtf(nn);
    }
}

// ---------------- topk (k=256 of 512) + MLP head, 256 threads ---------------
static __device__ void topk_mlp_graph(int g, const float* __restrict__ scores,
                                      const float* __restrict__ h,
                                      const float* __restrict__ fc1W,
                                      const float* __restrict__ fc1b,
                                      const float* __restrict__ fc2W,
                                      const float* __restrict__ fc2b,
                                      const float* __restrict__ fc3W,
                                      const float* __restrict__ fc3b,
                                      float* __restrict__ out, float* smem)
{
    float*  s   = smem;           // 512
    float*  w   = smem + 512;     // 256
    float*  pld = smem + 768;     // 128
    float*  z1  = smem + 896;     // 128
    float*  z2  = smem + 1024;    // 64
    int*    sel = (int*)(smem + 1088);     // 256
    float4* red = (float4*)(smem + 1344);  // 256 float4 (16B-aligned offset)
    const int i = threadIdx.x;

    s[i]       = scores[g * 512 + i];
    s[i + 256] = scores[g * 512 + 256 + i];
    __syncthreads();
#pragma unroll
    for (int half = 0; half < 2; half++) {
        const int idx = i + half * 256;
        const float si = s[idx];
        int rank = 0;
        for (int j = 0; j < 512; j++) {
            float sj = s[j];
            rank += (sj > si) || (sj == si && j < idx);
        }
        if (rank < 256) {
            sel[rank] = idx;
            w[rank]   = tanhf(si) * (1.f / 256.f);
        }
    }
    __syncthreads();
    const int c   = (i & 31) * 4;
    const int grp = i >> 5;            // 8 groups
    float4 acc = make_float4(0.f, 0.f, 0.f, 0.f);
    for (int t = grp; t < 256; t += 8) {
        acc = f4fma(w[t], *(const float4*)&h[((size_t)g * 512 + sel[t]) * 128 + c], acc);
    }
    red[i] = acc;
    __syncthreads();
    if (i < 128) red[i] = f4add(red[i], red[i + 128]);
    __syncthreads();
    if (i < 64) red[i] = f4add(red[i], red[i + 64]);
    __syncthreads();
    if (i < 32) {
        float4 v = f4add(red[i], red[i + 32]);
        *(float4*)&pld[i * 4] = v;
    }
    __syncthreads();
    if (i < 128) {
        float a = fc1b[i];
        for (int k = 0; k < 128; k++) a += pld[k] * fc1W[k * 128 + i];
        z1[i] = fmaxf(a, 0.f);
    }
    __syncthreads();
    if (i < 64) {
        float b = fc2b[i];
        for (int k = 0; k < 128; k++) b += z1[k] * fc2W[k * 64 + i];
        z2[i] = fmaxf(b, 0.f);
    }
    __syncthreads();
    if (i < 10) {
        float o = fc3b[i];
        for (int k = 0; k < 64; k++) o += z2[k] * fc3W[k * 10 + i];
        out[g * 10 + i] = o;
    }
    __syncthreads();
}

// ============================ The mega-kernel ===============================
__global__ __launch_bounds__(256) void fused_all(
    const float* __restrict__ x, const int* __restrict__ src,
    const int* __restrict__ dst,
    const float* __restrict__ embW, const float* __restrict__ embb,
    const float* __restrict__ gcnW, const float* __restrict__ gcnb,
    const float* __restrict__ poolp,
    const float* __restrict__ fc1W, const float* __restrict__ fc1b,
    const float* __restrict__ fc2W, const float* __restrict__ fc2b,
    const float* __restrict__ fc3W, const float* __restrict__ fc3b,
    float* __restrict__ out,
    float* __restrict__ h, float* __restrict__ hs,
    int* __restrict__ cnt, int* __restrict__ csr_pad,
    float* __restrict__ scores,
    float* __restrict__ W01, float* __restrict__ b01,
    int n, int E)
{
    cg::grid_group grid = cg::this_grid();
    __shared__ float smem[SMEM_FLOATS];
    const int nb  = gridDim.x;
    const int bid = blockIdx.x;
    const int tid = threadIdx.x;
    const int nt  = nb * 256;

    // phase 0: zero degree counters
    for (int i = bid * 256 + tid; i < n; i += nt) cnt[i] = 0;
    grid.sync();

    // phase 1: CSR build (grid-stride over edges) + weight fold (blocks <129)
    for (int e = bid * 256 + tid; e < E; e += nt) {
        int d = dst[e];
        int r = atomicAdd(&cnt[d], 1);
        if (r < SLOTS) csr_pad[d * SLOTS + r] = src[e];
    }
    if (bid < 129)
        fold_row(bid, embW, embb, gcnW, W01, b01, smem);
    grid.sync();

    const int tiles  = n / 128;   // 512
    const int groups = n / 8;     // 8192

    // layer 0
    for (int t = bid; t < tiles; t += nb) gemm_tile(x, W01, b01, cnt, hs, t, smem);
    grid.sync();
    for (int g = bid; g < groups; g += nb)
        agg_group(hs, csr_pad, cnt, gcnb, h, poolp, nullptr, g);
    grid.sync();
    // layer 1
    for (int t = bid; t < tiles; t += nb)
        gemm_tile(h, gcnW + 128 * 128, nullptr, cnt, hs, t, smem);
    grid.sync();
    for (int g = bid; g < groups; g += nb)
        agg_group(hs, csr_pad, cnt, gcnb + 128, h, poolp, nullptr, g);
    grid.sync();
    // layer 2 (score fused into aggregate)
    for (int t = bid; t < tiles; t += nb)
        gemm_tile(h, gcnW + 2 * 128 * 128, nullptr, cnt, hs, t, smem);
    grid.sync();
    for (int g = bid; g < groups; g += nb)
        agg_group(hs, csr_pad, cnt, gcnb + 256, h, poolp, scores, g);
    grid.sync();

    // final: topk pool + MLP head (one graph per block)
    for (int g = bid; g < n / 512; g += nb)
        topk_mlp_graph(g, scores, h, fc1W, fc1b, fc2W, fc2b, fc3W, fc3b,
                       out, smem);
}

// ============================ Launcher ======================================
extern "C" void kernel_launch(void* const* d_in, const int* in_sizes, int n_in,
                              void* d_out, int out_size, void* d_ws, size_t ws_size,
                              hipStream_t stream)
{
    const float* x     = (const float*)d_in[0];
    const int*   eidx  = (const int*)d_in[1];
    const float* embW  = (const float*)d_in[3];
    const float* embb  = (const float*)d_in[4];
    const float* gcnW  = (const float*)d_in[5];
    const float* gcnb  = (const float*)d_in[6];
    const float* poolp = (const float*)d_in[7];
    const float* fc1W  = (const float*)d_in[8];
    const float* fc1b  = (const float*)d_in[9];
    const float* fc2W  = (const float*)d_in[10];
    const float* fc2b  = (const float*)d_in[11];
    const float* fc3W  = (const float*)d_in[12];
    const float* fc3b  = (const float*)d_in[13];
    float* out = (float*)d_out;

    const int n = in_sizes[0] / 128;   // 65536
    const int E = in_sizes[1] / 2;     // 524288

    const int* src = eidx;
    const int* dst = eidx + E;

    char* ws = (char*)d_ws;
    size_t off = 0;
    auto carve = [&](size_t bytes) {
        void* p = ws + off;
        off += (bytes + 255) & ~(size_t)255;
        return p;
    };
    float* h       = (float*)carve((size_t)n * 128 * 4);
    float* hs      = (float*)carve((size_t)n * 128 * 4);
    int*   cnt     = (int*)carve((size_t)n * 4);
    int*   csr_pad = (int*)carve((size_t)n * SLOTS * 4);
    float* scores  = (float*)carve((size_t)n * 4);
    float* W01     = (float*)carve(128 * 128 * 4);
    float* b01     = (float*)carve(128 * 4);
    (void)ws_size;

    // co-resident grid size from the occupancy API (same value every call)
    int maxb = 0;
    hipOccupancyMaxActiveBlocksPerMultiprocessor(&maxb, fused_all, 256, 0);
    if (maxb < 1) maxb = 1;
    int grid = maxb * 256;             // 256 CUs
    if (grid < 256) grid = 256;        // need >=129 blocks for the fold phase

    void* args[] = {
        (void*)&x, (void*)&src, (void*)&dst,
        (void*)&embW, (void*)&embb, (void*)&gcnW, (void*)&gcnb,
        (void*)&poolp, (void*)&fc1W, (void*)&fc1b,
        (void*)&fc2W, (void*)&fc2b, (void*)&fc3W, (void*)&fc3b,
        (void*)&out, (void*)&h, (void*)&hs,
        (void*)&cnt, (void*)&csr_pad, (void*)&scores,
        (void*)&W01, (void*)&b01, (void*)&n, (void*)&E
    };
    hipLaunchCooperativeKernel((const void*)fused_all, dim3(grid), dim3(256),
                               args, 0, stream);
}